// Round 1
// baseline (3264.436 us; speedup 1.0000x reference)
//
#include <hip/hip_runtime.h>
#include <hip/hip_bf16.h>

typedef unsigned short u16;
typedef __attribute__((ext_vector_type(8))) short bf16x8;
typedef __attribute__((ext_vector_type(4))) float f32x4;

#define BT     4096
#define CDIM   1024
#define NH     16
#define FF     4096
#define DIN    128
#define DOUT   256
#define NLAYER 8
#define TSEQ   1024
#define NBATCH 4

__device__ inline u16 f2bfu(float v) {
    __hip_bfloat16 h = __float2bfloat16(v);
    return __builtin_bit_cast(unsigned short, h);
}

__device__ inline void async_copy16(const u16* g, u16* l) {
    __builtin_amdgcn_global_load_lds((const __attribute__((address_space(1))) void*)g,
                                     (__attribute__((address_space(3))) void*)l,
                                     16, 0, 0);
}

// ---------------- GEMM: C[M,N] = act(A[M,K] @ Bt[N,K]^T + bias) (+res) ----------------
// m97 structure: 128x128 tile, BK=32, 4 waves in 2x2, 4x4 mfma_16x16x32_bf16 per wave.
template<int ACT, int RES, int OBF>
__global__ __launch_bounds__(256) void gemm_bt(
    const u16* __restrict__ A, const u16* __restrict__ Bt,
    const float* __restrict__ bias, const float* res,
    void* outp, int M, int N, int K)
{
    __shared__ __align__(16) u16 As[128 * 32];
    __shared__ __align__(16) u16 Bs[128 * 32];
    int tid  = threadIdx.x;
    int wave = tid >> 6, lane = tid & 63;
    int ln = lane & 15, quad = lane >> 4;
    int wm = (wave >> 1) * 64, wn = (wave & 1) * 64;
    const u16* Ab = A  + (size_t)blockIdx.y * 128 * K;
    const u16* Bb = Bt + (size_t)blockIdx.x * 128 * K;
    f32x4 acc[4][4] = {};
    for (int kt = 0; kt < K; kt += 32) {
#pragma unroll
        for (int it = 0; it < 2; ++it) {
            int e = it * 256 + tid;
            int row = e >> 2, col = (e & 3) * 8;
            int lbase = (it * 256 + wave * 64) * 8;   // wave-uniform LDS base
            async_copy16(Ab + (size_t)row * K + kt + col, As + lbase);
            async_copy16(Bb + (size_t)row * K + kt + col, Bs + lbase);
        }
        __syncthreads();
        bf16x8 af[4], bfr[4];
#pragma unroll
        for (int i = 0; i < 4; ++i)
            af[i] = *(const bf16x8*)&As[(wm + i * 16 + ln) * 32 + quad * 8];
#pragma unroll
        for (int j = 0; j < 4; ++j)
            bfr[j] = *(const bf16x8*)&Bs[(wn + j * 16 + ln) * 32 + quad * 8];
#pragma unroll
        for (int i = 0; i < 4; ++i)
#pragma unroll
            for (int j = 0; j < 4; ++j)
                acc[i][j] = __builtin_amdgcn_mfma_f32_16x16x32_bf16(af[i], bfr[j], acc[i][j], 0, 0, 0);
        __syncthreads();
    }
    int gr0 = blockIdx.y * 128 + wm + quad * 4;
    int gc0 = blockIdx.x * 128 + wn + ln;
#pragma unroll
    for (int i = 0; i < 4; ++i) {
#pragma unroll
        for (int j = 0; j < 4; ++j) {
            int gc = gc0 + j * 16;
            float bv = bias[gc];
#pragma unroll
            for (int r = 0; r < 4; ++r) {
                int gr = gr0 + i * 16 + r;
                float v = acc[i][j][r] + bv;
                if (ACT == 1) v = 0.5f * v * (1.0f + erff(v * 0.70710678118654752f)); // exact gelu
                if (ACT == 2) v = tanhf(v);
                size_t idx = (size_t)gr * N + gc;
                if (RES) v += res[idx];
                if (OBF) ((u16*)outp)[idx] = f2bfu(v);
                else     ((float*)outp)[idx] = v;
            }
        }
    }
}

// ---------------- Flash attention: 1 wave per (b,h, 16-row q-tile), K-tiles of 32 ----------------
__global__ __launch_bounds__(64) void attn_kernel(const u16* __restrict__ qkv, u16* __restrict__ y)
{
    __shared__ __align__(16) u16 Plds[16 * 32];
    int qt = blockIdx.x, bh = blockIdx.y;
    int b = bh >> 4, h = bh & 15;
    int q0 = qt * 16;
    int lane = threadIdx.x;
    int ln = lane & 15, quad = lane >> 4;
    const int SC = 3 * CDIM;
    const u16* base = qkv + (size_t)b * TSEQ * SC;
    // Q A-frags (feat halves 0..31, 32..63)
    const u16* qrow = base + (size_t)(q0 + ln) * SC + h * 64 + quad * 8;
    bf16x8 qf0 = *(const bf16x8*)(qrow);
    bf16x8 qf1 = *(const bf16x8*)(qrow + 32);
    f32x4 O[4] = {};
    float m_i[4], l_i[4];
#pragma unroll
    for (int r = 0; r < 4; ++r) { m_i[r] = -1e30f; l_i[r] = 0.0f; }
    int nkt = qt / 2 + 1;
    for (int kt = 0; kt < nkt; ++kt) {
        int j0 = kt * 32;
        const u16* krow0 = base + (size_t)(j0 + ln) * SC + CDIM + h * 64;
        const u16* krow1 = base + (size_t)(j0 + 16 + ln) * SC + CDIM + h * 64;
        bf16x8 kf00 = *(const bf16x8*)(krow0 + quad * 8);
        bf16x8 kf01 = *(const bf16x8*)(krow0 + 32 + quad * 8);
        bf16x8 kf10 = *(const bf16x8*)(krow1 + quad * 8);
        bf16x8 kf11 = *(const bf16x8*)(krow1 + 32 + quad * 8);
        f32x4 S0 = {}, S1 = {};
        S0 = __builtin_amdgcn_mfma_f32_16x16x32_bf16(qf0, kf00, S0, 0, 0, 0);
        S0 = __builtin_amdgcn_mfma_f32_16x16x32_bf16(qf1, kf01, S0, 0, 0, 0);
        S1 = __builtin_amdgcn_mfma_f32_16x16x32_bf16(qf0, kf10, S1, 0, 0, 0);
        S1 = __builtin_amdgcn_mfma_f32_16x16x32_bf16(qf1, kf11, S1, 0, 0, 0);
        bool needmask = (j0 + 32 > q0);
        float alpha[4];
#pragma unroll
        for (int r = 0; r < 4; ++r) {
            float s0 = S0[r] * 0.125f, s1 = S1[r] * 0.125f;
            if (needmask) {
                int qr = q0 + quad * 4 + r;
                if (j0 + ln > qr)      s0 = -1e30f;
                if (j0 + 16 + ln > qr) s1 = -1e30f;
            }
            float mx = fmaxf(s0, s1);
            mx = fmaxf(mx, __shfl_xor(mx, 1));
            mx = fmaxf(mx, __shfl_xor(mx, 2));
            mx = fmaxf(mx, __shfl_xor(mx, 4));
            mx = fmaxf(mx, __shfl_xor(mx, 8));
            float mn = fmaxf(m_i[r], mx);
            float al = __expf(m_i[r] - mn);
            float p0 = __expf(s0 - mn);
            float p1 = __expf(s1 - mn);
            float rs = p0 + p1;
            rs += __shfl_xor(rs, 1);
            rs += __shfl_xor(rs, 2);
            rs += __shfl_xor(rs, 4);
            rs += __shfl_xor(rs, 8);
            l_i[r] = l_i[r] * al + rs;
            m_i[r] = mn;
            alpha[r] = al;
            // P: C-layout -> LDS row-major [qrow][key]
            Plds[(quad * 4 + r) * 32 + ln]      = f2bfu(p0);
            Plds[(quad * 4 + r) * 32 + 16 + ln] = f2bfu(p1);
        }
#pragma unroll
        for (int nt = 0; nt < 4; ++nt)
#pragma unroll
            for (int r = 0; r < 4; ++r)
                O[nt][r] *= alpha[r];
        __syncthreads();
        bf16x8 pa = *(const bf16x8*)&Plds[ln * 32 + quad * 8];   // A-layout read
        const u16* vrow = base + (size_t)(j0 + quad * 8) * SC + 2 * CDIM + h * 64 + ln;
#pragma unroll
        for (int nt = 0; nt < 4; ++nt) {
            bf16x8 vf;
#pragma unroll
            for (int jj = 0; jj < 8; ++jj)
                vf[jj] = (short)vrow[(size_t)jj * SC + nt * 16];
            O[nt] = __builtin_amdgcn_mfma_f32_16x16x32_bf16(pa, vf, O[nt], 0, 0, 0);
        }
        __syncthreads();
    }
#pragma unroll
    for (int r = 0; r < 4; ++r) {
        float invl = 1.0f / l_i[r];
        int row = q0 + quad * 4 + r;
#pragma unroll
        for (int nt = 0; nt < 4; ++nt)
            y[(size_t)(b * TSEQ + row) * CDIM + h * 64 + nt * 16 + ln] = f2bfu(O[nt][r] * invl);
    }
}

// ---------------- LayerNorm (row of NPT*256 fp32 -> bf16) ----------------
template<int NPT>
__global__ __launch_bounds__(256) void ln_kernel(const float* __restrict__ x,
    const float* __restrict__ g, const float* __restrict__ bet, u16* __restrict__ out)
{
    const int n = NPT * 256;
    int row = blockIdx.x, tid = threadIdx.x;
    const float* xr = x + (size_t)row * n;
    float xv[NPT];
    float s1 = 0.f, s2 = 0.f;
#pragma unroll
    for (int k = 0; k < NPT; ++k) {
        float v = xr[k * 256 + tid];
        xv[k] = v; s1 += v; s2 += v * v;
    }
#pragma unroll
    for (int m = 1; m < 64; m <<= 1) { s1 += __shfl_xor(s1, m); s2 += __shfl_xor(s2, m); }
    __shared__ float red[8];
    int wv = tid >> 6;
    if ((tid & 63) == 0) { red[wv] = s1; red[4 + wv] = s2; }
    __syncthreads();
    s1 = red[0] + red[1] + red[2] + red[3];
    s2 = red[4] + red[5] + red[6] + red[7];
    float mu = s1 * (1.0f / n);
    float var = s2 * (1.0f / n) - mu * mu;
    float rs = rsqrtf(var + 1e-5f);
#pragma unroll
    for (int k = 0; k < NPT; ++k) {
        int c = k * 256 + tid;
        out[(size_t)row * n + c] = f2bfu((xv[k] - mu) * rs * g[c] + bet[c]);
    }
}

// ---------------- 32x32 transpose + fp32->bf16: dst[N,K] = bf16(src[K,N]^T) ----------------
__device__ inline void tile_tc(const float* src, u16* dst, int K, int N, int kt, int nt,
                               int tid, float* sm)
{
    int c = tid & 31, r0 = tid >> 5;
#pragma unroll
    for (int rr = r0; rr < 32; rr += 8)
        sm[rr * 33 + c] = src[(size_t)(kt * 32 + rr) * N + nt * 32 + c];
    __syncthreads();
#pragma unroll
    for (int rr = r0; rr < 32; rr += 8)
        dst[(size_t)(nt * 32 + rr) * K + kt * 32 + c] = f2bfu(sm[c * 33 + rr]);
}

__global__ __launch_bounds__(256) void transpose_cvt(const float* __restrict__ src,
    u16* __restrict__ dst, int K, int N)
{
    __shared__ float sm[32 * 33];
    tile_tc(src, dst, K, N, blockIdx.y, blockIdx.x, threadIdx.x, sm);
}

// Fused per-layer weight prep: Wq/Wk/Wv -> qkv_t, Wo -> wo_t, W1 -> w1_t, W2 -> w2_t, bias concat
__global__ __launch_bounds__(256) void prep_layer(
    const float* __restrict__ Wq, const float* __restrict__ Wk, const float* __restrict__ Wv,
    const float* __restrict__ Wo, const float* __restrict__ W1, const float* __restrict__ W2,
    const float* __restrict__ bq, const float* __restrict__ bk, const float* __restrict__ bv,
    u16* __restrict__ qkv_t, u16* __restrict__ wo_t, u16* __restrict__ w1_t,
    u16* __restrict__ w2_t, float* __restrict__ bias3)
{
    __shared__ float sm[32 * 33];
    int id = blockIdx.x, tid = threadIdx.x;
    const float* src; u16* dst; int K, N, kt, nt;
    if (id < 3072) {
        int w = id >> 10, t = id & 1023;
        src = (w == 0) ? Wq : ((w == 1) ? Wk : Wv);
        dst = qkv_t + (size_t)w * CDIM * CDIM;
        K = CDIM; N = CDIM; kt = t >> 5; nt = t & 31;
    } else if (id < 4096) {
        int t = id - 3072; src = Wo; dst = wo_t; K = CDIM; N = CDIM; kt = t >> 5; nt = t & 31;
    } else if (id < 8192) {
        int t = id - 4096; src = W1; dst = w1_t; K = CDIM; N = FF;   kt = t >> 7; nt = t & 127;
    } else {
        int t = id - 8192; src = W2; dst = w2_t; K = FF;   N = CDIM; kt = t >> 5; nt = t & 31;
    }
    tile_tc(src, dst, K, N, kt, nt, tid, sm);
    if (id < 3) {
        const float* bsrc = (id == 0) ? bq : ((id == 1) ? bk : bv);
        for (int k2 = tid; k2 < CDIM; k2 += 256) bias3[id * CDIM + k2] = bsrc[k2];
    }
}

__global__ __launch_bounds__(256) void cvt_bf16(const float* __restrict__ src,
    u16* __restrict__ dst, int n)
{
    int i = blockIdx.x * 256 + threadIdx.x;
    if (i < n) dst[i] = f2bfu(src[i]);
}

__global__ __launch_bounds__(256) void out_sub(const float* __restrict__ pred,
    const float* __restrict__ x, float* __restrict__ out, int total)
{
    int i = blockIdx.x * 256 + threadIdx.x;
    if (i >= total) return;
    int b = i / ((TSEQ - 1) * DIN);
    int rtmp = i - b * (TSEQ - 1) * DIN;
    int t = rtmp >> 7, f = rtmp & 127;
    out[i] = pred[(size_t)(b * TSEQ + t) * DIN + f] - x[(size_t)(b * TSEQ + t + 1) * DIN + f];
}

__global__ void fail_flag(float* out) { if (threadIdx.x == 0 && blockIdx.x == 0) out[0] = 1.0e6f; }

extern "C" void kernel_launch(void* const* d_in, const int* in_sizes, int n_in,
                              void* d_out, int out_size, void* d_ws, size_t ws_size,
                              hipStream_t stream)
{
    (void)in_sizes; (void)n_in; (void)out_size;
    const float* tokens    = (const float*)d_in[0];
    const float* tok_emb_w = (const float*)d_in[1];
    const float* tok_emb_b = (const float*)d_in[2];
    const float* ln1_g = (const float*)d_in[3];
    const float* ln1_b = (const float*)d_in[4];
    const float* Wq = (const float*)d_in[5];
    const float* bq = (const float*)d_in[6];
    const float* Wk = (const float*)d_in[7];
    const float* bk = (const float*)d_in[8];
    const float* Wv = (const float*)d_in[9];
    const float* bv = (const float*)d_in[10];
    const float* Wo = (const float*)d_in[11];
    const float* bo = (const float*)d_in[12];
    const float* ln2_g = (const float*)d_in[13];
    const float* ln2_b = (const float*)d_in[14];
    const float* W1 = (const float*)d_in[15];
    const float* b1 = (const float*)d_in[16];
    const float* W2 = (const float*)d_in[17];
    const float* b2 = (const float*)d_in[18];
    const float* lnf_g = (const float*)d_in[19];
    const float* lnf_b = (const float*)d_in[20];
    const float* proj_w = (const float*)d_in[21];
    const float* proj_b = (const float*)d_in[22];
    const float* dec_w1 = (const float*)d_in[23];
    const float* dec_b1 = (const float*)d_in[24];
    const float* dec_ln_g = (const float*)d_in[25];
    const float* dec_ln_b = (const float*)d_in[26];
    const float* dec_w2 = (const float*)d_in[27];
    const float* dec_b2 = (const float*)d_in[28];

    char* p = (char*)d_ws;
    auto alloc = [&](size_t bytes) -> char* {
        char* r = p; p += (bytes + 255) & ~(size_t)255; return r;
    };
    u16*   xb     = (u16*)  alloc((size_t)BT * DIN * 2);
    float* h      = (float*)alloc((size_t)BT * CDIM * 4);
    u16*   abuf   = (u16*)  alloc((size_t)BT * CDIM * 2);
    u16*   qkvb   = (u16*)  alloc((size_t)BT * 3 * CDIM * 2);
    u16*   yb     = (u16*)  alloc((size_t)BT * CDIM * 2);
    u16*   t1     = (u16*)  alloc((size_t)BT * FF * 2);
    u16*   feats  = (u16*)  alloc((size_t)BT * DOUT * 2);
    float* d1     = (float*)alloc((size_t)BT * DOUT * 4);
    u16*   d1n    = (u16*)  alloc((size_t)BT * DOUT * 2);
    float* pred   = (float*)alloc((size_t)BT * DIN * 4);
    u16*   emb_t  = (u16*)  alloc((size_t)CDIM * DIN * 2);
    u16*   proj_t = (u16*)  alloc((size_t)DOUT * CDIM * 2);
    u16*   dec1_t = (u16*)  alloc((size_t)DOUT * DOUT * 2);
    u16*   dec2_t = (u16*)  alloc((size_t)DIN * DOUT * 2);
    u16*   qkv_t  = (u16*)  alloc((size_t)3 * CDIM * CDIM * 2);
    u16*   wo_t   = (u16*)  alloc((size_t)CDIM * CDIM * 2);
    u16*   w1_t   = (u16*)  alloc((size_t)FF * CDIM * 2);
    u16*   w2_t   = (u16*)  alloc((size_t)CDIM * FF * 2);
    float* bias3  = (float*)alloc((size_t)3 * CDIM * 4);
    if ((size_t)(p - (char*)d_ws) > ws_size) {
        fail_flag<<<1, 64, 0, stream>>>((float*)d_out);
        return;
    }

    cvt_bf16<<<(BT * DIN) / 256, 256, 0, stream>>>(tokens, xb, BT * DIN);
    transpose_cvt<<<dim3(CDIM / 32, DIN / 32),  256, 0, stream>>>(tok_emb_w, emb_t,  DIN,  CDIM);
    transpose_cvt<<<dim3(DOUT / 32, CDIM / 32), 256, 0, stream>>>(proj_w,    proj_t, CDIM, DOUT);
    transpose_cvt<<<dim3(DOUT / 32, DOUT / 32), 256, 0, stream>>>(dec_w1,    dec1_t, DOUT, DOUT);
    transpose_cvt<<<dim3(DIN / 32,  DOUT / 32), 256, 0, stream>>>(dec_w2,    dec2_t, DOUT, DIN);
    // h = xb @ emb_t^T + b  (fp32 out)
    gemm_bt<0, 0, 0><<<dim3(CDIM / 128, BT / 128), 256, 0, stream>>>(
        xb, emb_t, tok_emb_b, nullptr, h, BT, CDIM, DIN);

    for (int l = 0; l < NLAYER; ++l) {
        prep_layer<<<12288, 256, 0, stream>>>(
            Wq + (size_t)l * CDIM * CDIM, Wk + (size_t)l * CDIM * CDIM,
            Wv + (size_t)l * CDIM * CDIM, Wo + (size_t)l * CDIM * CDIM,
            W1 + (size_t)l * CDIM * FF,   W2 + (size_t)l * FF * CDIM,
            bq + l * CDIM, bk + l * CDIM, bv + l * CDIM,
            qkv_t, wo_t, w1_t, w2_t, bias3);
        ln_kernel<4><<<BT, 256, 0, stream>>>(h, ln1_g + l * CDIM, ln1_b + l * CDIM, abuf);
        gemm_bt<0, 0, 1><<<dim3(3 * CDIM / 128, BT / 128), 256, 0, stream>>>(
            abuf, qkv_t, bias3, nullptr, qkvb, BT, 3 * CDIM, CDIM);
        attn_kernel<<<dim3(TSEQ / 16, NBATCH * NH), 64, 0, stream>>>(qkvb, yb);
        gemm_bt<0, 1, 0><<<dim3(CDIM / 128, BT / 128), 256, 0, stream>>>(
            yb, wo_t, bo + l * CDIM, h, h, BT, CDIM, CDIM);
        ln_kernel<4><<<BT, 256, 0, stream>>>(h, ln2_g + l * CDIM, ln2_b + l * CDIM, abuf);
        gemm_bt<1, 0, 1><<<dim3(FF / 128, BT / 128), 256, 0, stream>>>(
            abuf, w1_t, b1 + l * FF, nullptr, t1, BT, FF, CDIM);
        gemm_bt<0, 1, 0><<<dim3(CDIM / 128, BT / 128), 256, 0, stream>>>(
            t1, w2_t, b2 + l * CDIM, h, h, BT, CDIM, FF);
    }

    ln_kernel<4><<<BT, 256, 0, stream>>>(h, lnf_g, lnf_b, abuf);
    gemm_bt<0, 0, 1><<<dim3(DOUT / 128, BT / 128), 256, 0, stream>>>(
        abuf, proj_t, proj_b, nullptr, feats, BT, DOUT, CDIM);
    gemm_bt<2, 0, 0><<<dim3(DOUT / 128, BT / 128), 256, 0, stream>>>(
        feats, dec1_t, dec_b1, nullptr, d1, BT, DOUT, DOUT);
    ln_kernel<1><<<BT, 256, 0, stream>>>(d1, dec_ln_g, dec_ln_b, d1n);
    gemm_bt<0, 0, 0><<<dim3(DIN / 128, BT / 128), 256, 0, stream>>>(
        d1n, dec2_t, dec_b2, nullptr, pred, BT, DIN, DOUT);
    int total = NBATCH * (TSEQ - 1) * DIN;
    out_sub<<<(total + 255) / 256, 256, 0, stream>>>(pred, tokens, (float*)d_out, total);
}

// Round 2
// 3137.490 us; speedup vs baseline: 1.0405x; 1.0405x over previous
//
#include <hip/hip_runtime.h>
#include <hip/hip_bf16.h>

typedef unsigned short u16;
typedef __attribute__((ext_vector_type(8))) short bf16x8;
typedef __attribute__((ext_vector_type(4))) float f32x4;

#define BT     4096
#define CDIM   1024
#define NH     16
#define FF     4096
#define DIN    128
#define DOUT   256
#define NLAYER 8
#define TSEQ   1024
#define NBATCH 4

__device__ inline u16 f2bfu(float v) {
    __hip_bfloat16 h = __float2bfloat16(v);
    return __builtin_bit_cast(unsigned short, h);
}

__device__ inline void async_copy16(const u16* g, u16* l) {
    __builtin_amdgcn_global_load_lds((const __attribute__((address_space(1))) void*)g,
                                     (__attribute__((address_space(3))) void*)l,
                                     16, 0, 0);
}

// ---------------- GEMM: C[M,N] = act(A[M,K] @ Bt[N,K]^T + bias) ----------------
// 128x128 tile, BK=32, 4 waves 2x2, 4x4 mfma_16x16x32_bf16 per wave.
// EPI: 0 = store (OBF: bf16/f32, RES: +res, ACT: 0 none / 1 gelu / 2 tanh)
//      1 = f32 atomicAdd into outp (split-K; bias added by z==0 only)
//      2 = QKV split store: cols<2048 -> qk row-major (stride 2048), cols>=2048 -> vT[b,h,f,t]
template<int ACT, int RES, int OBF, int EPI>
__global__ __launch_bounds__(256) void gemm_bt(
    const u16* __restrict__ A, const u16* __restrict__ Bt,
    const float* __restrict__ bias, const float* res,
    void* outp, u16* __restrict__ vtp, int N, int K, int Kc)
{
    __shared__ __align__(16) u16 As[128 * 32];
    __shared__ __align__(16) u16 Bs[128 * 32];
    int tid  = threadIdx.x;
    int wave = tid >> 6, lane = tid & 63;
    int ln = lane & 15, quad = lane >> 4;
    int wm = (wave >> 1) * 64, wn = (wave & 1) * 64;
    int k0 = blockIdx.z * Kc;
    const u16* Ab = A  + (size_t)blockIdx.y * 128 * K;
    const u16* Bb = Bt + (size_t)blockIdx.x * 128 * K;
    f32x4 acc[4][4] = {};
    for (int kt = k0; kt < k0 + Kc; kt += 32) {
#pragma unroll
        for (int it = 0; it < 2; ++it) {
            int e = it * 256 + tid;
            int row = e >> 2, col = (e & 3) * 8;
            int lbase = (it * 256 + wave * 64) * 8;   // wave-uniform LDS base
            async_copy16(Ab + (size_t)row * K + kt + col, As + lbase);
            async_copy16(Bb + (size_t)row * K + kt + col, Bs + lbase);
        }
        __syncthreads();
        bf16x8 af[4], bfr[4];
#pragma unroll
        for (int i = 0; i < 4; ++i)
            af[i] = *(const bf16x8*)&As[(wm + i * 16 + ln) * 32 + quad * 8];
#pragma unroll
        for (int j = 0; j < 4; ++j)
            bfr[j] = *(const bf16x8*)&Bs[(wn + j * 16 + ln) * 32 + quad * 8];
#pragma unroll
        for (int i = 0; i < 4; ++i)
#pragma unroll
            for (int j = 0; j < 4; ++j)
                acc[i][j] = __builtin_amdgcn_mfma_f32_16x16x32_bf16(af[i], bfr[j], acc[i][j], 0, 0, 0);
        __syncthreads();
    }
    int gr0 = blockIdx.y * 128 + wm + quad * 4;
    int gc0 = blockIdx.x * 128 + wn + ln;
#pragma unroll
    for (int i = 0; i < 4; ++i) {
#pragma unroll
        for (int j = 0; j < 4; ++j) {
            int gc = gc0 + j * 16;
            float bv = (EPI == 1) ? ((blockIdx.z == 0) ? bias[gc] : 0.0f) : bias[gc];
#pragma unroll
            for (int r = 0; r < 4; ++r) {
                int gr = gr0 + i * 16 + r;
                float v = acc[i][j][r] + bv;
                if (ACT == 1) v = 0.5f * v * (1.0f + erff(v * 0.70710678118654752f)); // exact gelu
                if (ACT == 2) v = tanhf(v);
                if (EPI == 1) {
                    unsafeAtomicAdd(&((float*)outp)[(size_t)gr * N + gc], v);
                } else if (EPI == 2) {
                    if ((int)blockIdx.x < 16) {
                        ((u16*)outp)[(size_t)gr * 2048 + gc] = f2bfu(v);
                    } else {
                        int c2 = gc - 2048;
                        int hh = c2 >> 6, f = c2 & 63;
                        int bb = gr >> 10, t = gr & 1023;
                        vtp[((size_t)(bb * 16 + hh) * 64 + f) * TSEQ + t] = f2bfu(v);
                    }
                } else {
                    size_t idx = (size_t)gr * N + gc;
                    if (RES) v += res[idx];
                    if (OBF) ((u16*)outp)[idx] = f2bfu(v);
                    else     ((float*)outp)[idx] = v;
                }
            }
        }
    }
}

// ---------------- Flash attention v2: 1 wave per (b,h, 32-row q-block) ----------------
// qk: [b, t, 2048] (Q cols 0..1023, K cols 1024..2047), vT: [b*16+h, f(64), t]
__global__ __launch_bounds__(64) void attn_kernel(const u16* __restrict__ qk,
    const u16* __restrict__ vT, u16* __restrict__ y)
{
    __shared__ __align__(16) u16 Plds[2][16 * 32];
    int qt = blockIdx.x, bh = blockIdx.y;
    int b = bh >> 4, h = bh & 15;
    int q0 = qt * 32;
    int lane = threadIdx.x;
    int ln = lane & 15, quad = lane >> 4;
    const u16* qbase = qk + (size_t)b * TSEQ * 2048;
    bf16x8 qf[2][2];
#pragma unroll
    for (int qi = 0; qi < 2; ++qi) {
        const u16* qrow = qbase + (size_t)(q0 + qi * 16 + ln) * 2048 + h * 64 + quad * 8;
        qf[qi][0] = *(const bf16x8*)qrow;
        qf[qi][1] = *(const bf16x8*)(qrow + 32);
    }
    const u16* vbase = vT + (size_t)bh * 64 * TSEQ;
    f32x4 O[2][4] = {};
    float m_i[2][4], l_i[2][4];
#pragma unroll
    for (int qi = 0; qi < 2; ++qi)
#pragma unroll
        for (int r = 0; r < 4; ++r) { m_i[qi][r] = -1e30f; l_i[qi][r] = 0.0f; }
    int nkt = qt + 1;
    for (int kt = 0; kt < nkt; ++kt) {
        int j0 = kt * 32;
        bf16x8 kf[2][2];
#pragma unroll
        for (int kk = 0; kk < 2; ++kk) {
            const u16* krow = qbase + (size_t)(j0 + kk * 16 + ln) * 2048 + 1024 + h * 64 + quad * 8;
            kf[kk][0] = *(const bf16x8*)krow;
            kf[kk][1] = *(const bf16x8*)(krow + 32);
        }
        f32x4 S[2][2] = {};
#pragma unroll
        for (int qi = 0; qi < 2; ++qi)
#pragma unroll
            for (int kk = 0; kk < 2; ++kk) {
                S[qi][kk] = __builtin_amdgcn_mfma_f32_16x16x32_bf16(qf[qi][0], kf[kk][0], S[qi][kk], 0, 0, 0);
                S[qi][kk] = __builtin_amdgcn_mfma_f32_16x16x32_bf16(qf[qi][1], kf[kk][1], S[qi][kk], 0, 0, 0);
            }
        bool lastt = (kt == qt);
        float alpha[2][4];
#pragma unroll
        for (int qi = 0; qi < 2; ++qi) {
#pragma unroll
            for (int r = 0; r < 4; ++r) {
                float s0 = S[qi][0][r] * 0.125f, s1 = S[qi][1][r] * 0.125f;
                if (lastt) {
                    int qr = q0 + qi * 16 + quad * 4 + r;
                    if (j0 + ln > qr)      s0 = -1e30f;
                    if (j0 + 16 + ln > qr) s1 = -1e30f;
                }
                float mx = fmaxf(s0, s1);
                mx = fmaxf(mx, __shfl_xor(mx, 1));
                mx = fmaxf(mx, __shfl_xor(mx, 2));
                mx = fmaxf(mx, __shfl_xor(mx, 4));
                mx = fmaxf(mx, __shfl_xor(mx, 8));
                float mn = fmaxf(m_i[qi][r], mx);
                float al = __expf(m_i[qi][r] - mn);
                float p0 = __expf(s0 - mn);
                float p1 = __expf(s1 - mn);
                float rs = p0 + p1;
                rs += __shfl_xor(rs, 1);
                rs += __shfl_xor(rs, 2);
                rs += __shfl_xor(rs, 4);
                rs += __shfl_xor(rs, 8);
                l_i[qi][r] = l_i[qi][r] * al + rs;
                m_i[qi][r] = mn;
                alpha[qi][r] = al;
                Plds[qi][(quad * 4 + r) * 32 + ln]      = f2bfu(p0);
                Plds[qi][(quad * 4 + r) * 32 + 16 + ln] = f2bfu(p1);
            }
#pragma unroll
            for (int nt = 0; nt < 4; ++nt)
#pragma unroll
                for (int r = 0; r < 4; ++r)
                    O[qi][nt][r] *= alpha[qi][r];
        }
        __syncthreads();
        bf16x8 pa0 = *(const bf16x8*)&Plds[0][ln * 32 + quad * 8];
        bf16x8 pa1 = *(const bf16x8*)&Plds[1][ln * 32 + quad * 8];
#pragma unroll
        for (int nt = 0; nt < 4; ++nt) {
            bf16x8 vf = *(const bf16x8*)(vbase + (size_t)(nt * 16 + ln) * TSEQ + j0 + quad * 8);
            O[0][nt] = __builtin_amdgcn_mfma_f32_16x16x32_bf16(pa0, vf, O[0][nt], 0, 0, 0);
            O[1][nt] = __builtin_amdgcn_mfma_f32_16x16x32_bf16(pa1, vf, O[1][nt], 0, 0, 0);
        }
        __syncthreads();
    }
#pragma unroll
    for (int qi = 0; qi < 2; ++qi)
#pragma unroll
        for (int r = 0; r < 4; ++r) {
            float invl = 1.0f / l_i[qi][r];
            int row = q0 + qi * 16 + quad * 4 + r;
#pragma unroll
            for (int nt = 0; nt < 4; ++nt)
                y[(size_t)(b * TSEQ + row) * CDIM + h * 64 + nt * 16 + ln] = f2bfu(O[qi][nt][r] * invl);
        }
}

// ---------------- LayerNorm (row of NPT*256 fp32 -> bf16) ----------------
template<int NPT>
__global__ __launch_bounds__(256) void ln_kernel(const float* __restrict__ x,
    const float* __restrict__ g, const float* __restrict__ bet, u16* __restrict__ out)
{
    const int n = NPT * 256;
    int row = blockIdx.x, tid = threadIdx.x;
    const float* xr = x + (size_t)row * n;
    float xv[NPT];
    float s1 = 0.f, s2 = 0.f;
#pragma unroll
    for (int k = 0; k < NPT; ++k) {
        float v = xr[k * 256 + tid];
        xv[k] = v; s1 += v; s2 += v * v;
    }
#pragma unroll
    for (int m = 1; m < 64; m <<= 1) { s1 += __shfl_xor(s1, m); s2 += __shfl_xor(s2, m); }
    __shared__ float red[8];
    int wv = tid >> 6;
    if ((tid & 63) == 0) { red[wv] = s1; red[4 + wv] = s2; }
    __syncthreads();
    s1 = red[0] + red[1] + red[2] + red[3];
    s2 = red[4] + red[5] + red[6] + red[7];
    float mu = s1 * (1.0f / n);
    float var = s2 * (1.0f / n) - mu * mu;
    float rs = rsqrtf(var + 1e-5f);
#pragma unroll
    for (int k = 0; k < NPT; ++k) {
        int c = k * 256 + tid;
        out[(size_t)row * n + c] = f2bfu((xv[k] - mu) * rs * g[c] + bet[c]);
    }
}

// ---------------- 32x32 transpose + fp32->bf16: dst[N,K] = bf16(src[K,N]^T) ----------------
__device__ inline void tile_tc(const float* src, u16* dst, int K, int N, int kt, int nt,
                               int tid, float* sm)
{
    int c = tid & 31, r0 = tid >> 5;
#pragma unroll
    for (int rr = r0; rr < 32; rr += 8)
        sm[rr * 33 + c] = src[(size_t)(kt * 32 + rr) * N + nt * 32 + c];
    __syncthreads();
#pragma unroll
    for (int rr = r0; rr < 32; rr += 8)
        dst[(size_t)(nt * 32 + rr) * K + kt * 32 + c] = f2bfu(sm[c * 33 + rr]);
}

__global__ __launch_bounds__(256) void transpose_cvt(const float* __restrict__ src,
    u16* __restrict__ dst, int K, int N)
{
    __shared__ float sm[32 * 33];
    tile_tc(src, dst, K, N, blockIdx.y, blockIdx.x, threadIdx.x, sm);
}

// Fused per-layer weight prep
__global__ __launch_bounds__(256) void prep_layer(
    const float* __restrict__ Wq, const float* __restrict__ Wk, const float* __restrict__ Wv,
    const float* __restrict__ Wo, const float* __restrict__ W1, const float* __restrict__ W2,
    const float* __restrict__ bq, const float* __restrict__ bk, const float* __restrict__ bv,
    u16* __restrict__ qkv_t, u16* __restrict__ wo_t, u16* __restrict__ w1_t,
    u16* __restrict__ w2_t, float* __restrict__ bias3)
{
    __shared__ float sm[32 * 33];
    int id = blockIdx.x, tid = threadIdx.x;
    const float* src; u16* dst; int K, N, kt, nt;
    if (id < 3072) {
        int w = id >> 10, t = id & 1023;
        src = (w == 0) ? Wq : ((w == 1) ? Wk : Wv);
        dst = qkv_t + (size_t)w * CDIM * CDIM;
        K = CDIM; N = CDIM; kt = t >> 5; nt = t & 31;
    } else if (id < 4096) {
        int t = id - 3072; src = Wo; dst = wo_t; K = CDIM; N = CDIM; kt = t >> 5; nt = t & 31;
    } else if (id < 8192) {
        int t = id - 4096; src = W1; dst = w1_t; K = CDIM; N = FF;   kt = t >> 7; nt = t & 127;
    } else {
        int t = id - 8192; src = W2; dst = w2_t; K = FF;   N = CDIM; kt = t >> 5; nt = t & 31;
    }
    tile_tc(src, dst, K, N, kt, nt, tid, sm);
    if (id < 3) {
        const float* bsrc = (id == 0) ? bq : ((id == 1) ? bk : bv);
        for (int k2 = tid; k2 < CDIM; k2 += 256) bias3[id * CDIM + k2] = bsrc[k2];
    }
}

__global__ __launch_bounds__(256) void cvt_bf16(const float* __restrict__ src,
    u16* __restrict__ dst, int n)
{
    int i = blockIdx.x * 256 + threadIdx.x;
    if (i < n) dst[i] = f2bfu(src[i]);
}

__global__ __launch_bounds__(256) void zero_f32(float* __restrict__ dst, int n)
{
    int i = blockIdx.x * 256 + threadIdx.x;
    if (i < n) dst[i] = 0.0f;
}

__global__ __launch_bounds__(256) void out_sub(const float* __restrict__ pred,
    const float* __restrict__ x, float* __restrict__ out, int total)
{
    int i = blockIdx.x * 256 + threadIdx.x;
    if (i >= total) return;
    int b = i / ((TSEQ - 1) * DIN);
    int rtmp = i - b * (TSEQ - 1) * DIN;
    int t = rtmp >> 7, f = rtmp & 127;
    out[i] = pred[(size_t)(b * TSEQ + t) * DIN + f] - x[(size_t)(b * TSEQ + t + 1) * DIN + f];
}

__global__ void fail_flag(float* out) { if (threadIdx.x == 0 && blockIdx.x == 0) out[0] = 1.0e6f; }

extern "C" void kernel_launch(void* const* d_in, const int* in_sizes, int n_in,
                              void* d_out, int out_size, void* d_ws, size_t ws_size,
                              hipStream_t stream)
{
    (void)in_sizes; (void)n_in; (void)out_size;
    const float* tokens    = (const float*)d_in[0];
    const float* tok_emb_w = (const float*)d_in[1];
    const float* tok_emb_b = (const float*)d_in[2];
    const float* ln1_g = (const float*)d_in[3];
    const float* ln1_b = (const float*)d_in[4];
    const float* Wq = (const float*)d_in[5];
    const float* bq = (const float*)d_in[6];
    const float* Wk = (const float*)d_in[7];
    const float* bk = (const float*)d_in[8];
    const float* Wv = (const float*)d_in[9];
    const float* bv = (const float*)d_in[10];
    const float* Wo = (const float*)d_in[11];
    const float* bo = (const float*)d_in[12];
    const float* ln2_g = (const float*)d_in[13];
    const float* ln2_b = (const float*)d_in[14];
    const float* W1 = (const float*)d_in[15];
    const float* b1 = (const float*)d_in[16];
    const float* W2 = (const float*)d_in[17];
    const float* b2 = (const float*)d_in[18];
    const float* lnf_g = (const float*)d_in[19];
    const float* lnf_b = (const float*)d_in[20];
    const float* proj_w = (const float*)d_in[21];
    const float* proj_b = (const float*)d_in[22];
    const float* dec_w1 = (const float*)d_in[23];
    const float* dec_b1 = (const float*)d_in[24];
    const float* dec_ln_g = (const float*)d_in[25];
    const float* dec_ln_b = (const float*)d_in[26];
    const float* dec_w2 = (const float*)d_in[27];
    const float* dec_b2 = (const float*)d_in[28];

    char* p = (char*)d_ws;
    auto alloc = [&](size_t bytes) -> char* {
        char* r = p; p += (bytes + 255) & ~(size_t)255; return r;
    };
    u16*   xb      = (u16*)  alloc((size_t)BT * DIN * 2);
    float* h       = (float*)alloc((size_t)BT * CDIM * 4);
    u16*   abuf    = (u16*)  alloc((size_t)BT * CDIM * 2);
    u16*   qkb     = (u16*)  alloc((size_t)BT * 2048 * 2);       // Q,K
    u16*   vTb     = (u16*)  alloc((size_t)NBATCH * NH * 64 * TSEQ * 2);  // V transposed
    u16*   yb      = (u16*)  alloc((size_t)BT * CDIM * 2);
    u16*   t1      = (u16*)  alloc((size_t)BT * FF * 2);
    u16*   feats   = (u16*)  alloc((size_t)BT * DOUT * 2);
    float* projacc = (float*)alloc((size_t)BT * DOUT * 4);
    float* d1      = (float*)alloc((size_t)BT * DOUT * 4);
    u16*   d1n     = (u16*)  alloc((size_t)BT * DOUT * 2);
    float* pred    = (float*)alloc((size_t)BT * DIN * 4);
    u16*   emb_t   = (u16*)  alloc((size_t)CDIM * DIN * 2);
    u16*   proj_t  = (u16*)  alloc((size_t)DOUT * CDIM * 2);
    u16*   dec1_t  = (u16*)  alloc((size_t)DOUT * DOUT * 2);
    u16*   dec2_t  = (u16*)  alloc((size_t)DIN * DOUT * 2);
    u16*   qkv_t   = (u16*)  alloc((size_t)3 * CDIM * CDIM * 2);
    u16*   wo_t    = (u16*)  alloc((size_t)CDIM * CDIM * 2);
    u16*   w1_t    = (u16*)  alloc((size_t)FF * CDIM * 2);
    u16*   w2_t    = (u16*)  alloc((size_t)CDIM * FF * 2);
    float* bias3   = (float*)alloc((size_t)3 * CDIM * 4);
    if ((size_t)(p - (char*)d_ws) > ws_size) {
        fail_flag<<<1, 64, 0, stream>>>((float*)d_out);
        return;
    }

    cvt_bf16<<<(BT * DIN) / 256, 256, 0, stream>>>(tokens, xb, BT * DIN);
    transpose_cvt<<<dim3(CDIM / 32, DIN / 32),  256, 0, stream>>>(tok_emb_w, emb_t,  DIN,  CDIM);
    transpose_cvt<<<dim3(DOUT / 32, CDIM / 32), 256, 0, stream>>>(proj_w,    proj_t, CDIM, DOUT);
    transpose_cvt<<<dim3(DOUT / 32, DOUT / 32), 256, 0, stream>>>(dec_w1,    dec1_t, DOUT, DOUT);
    transpose_cvt<<<dim3(DIN / 32,  DOUT / 32), 256, 0, stream>>>(dec_w2,    dec2_t, DOUT, DIN);
    // h = xb @ emb_t^T + b  (fp32 out)
    gemm_bt<0, 0, 0, 0><<<dim3(CDIM / 128, BT / 128, 1), 256, 0, stream>>>(
        xb, emb_t, tok_emb_b, nullptr, h, nullptr, CDIM, DIN, DIN);

    for (int l = 0; l < NLAYER; ++l) {
        prep_layer<<<12288, 256, 0, stream>>>(
            Wq + (size_t)l * CDIM * CDIM, Wk + (size_t)l * CDIM * CDIM,
            Wv + (size_t)l * CDIM * CDIM, Wo + (size_t)l * CDIM * CDIM,
            W1 + (size_t)l * CDIM * FF,   W2 + (size_t)l * FF * CDIM,
            bq + l * CDIM, bk + l * CDIM, bv + l * CDIM,
            qkv_t, wo_t, w1_t, w2_t, bias3);
        ln_kernel<4><<<BT, 256, 0, stream>>>(h, ln1_g + l * CDIM, ln1_b + l * CDIM, abuf);
        // QKV: Q,K -> qkb, V -> vTb (transposed)
        gemm_bt<0, 0, 1, 2><<<dim3(3 * CDIM / 128, BT / 128, 1), 256, 0, stream>>>(
            abuf, qkv_t, bias3, nullptr, qkb, vTb, 3 * CDIM, CDIM, CDIM);
        attn_kernel<<<dim3(TSEQ / 32, NBATCH * NH), 64, 0, stream>>>(qkb, vTb, yb);
        // o-proj: split-K=2, atomic into residual h
        gemm_bt<0, 0, 0, 1><<<dim3(CDIM / 128, BT / 128, 2), 256, 0, stream>>>(
            yb, wo_t, bo + l * CDIM, nullptr, h, nullptr, CDIM, CDIM, CDIM / 2);
        ln_kernel<4><<<BT, 256, 0, stream>>>(h, ln2_g + l * CDIM, ln2_b + l * CDIM, abuf);
        gemm_bt<1, 0, 1, 0><<<dim3(FF / 128, BT / 128, 1), 256, 0, stream>>>(
            abuf, w1_t, b1 + l * FF, nullptr, t1, nullptr, FF, CDIM, CDIM);
        // MLP2: split-K=2, atomic into residual h
        gemm_bt<0, 0, 0, 1><<<dim3(CDIM / 128, BT / 128, 2), 256, 0, stream>>>(
            t1, w2_t, b2 + l * CDIM, nullptr, h, nullptr, CDIM, FF, FF / 2);
    }

    ln_kernel<4><<<BT, 256, 0, stream>>>(h, lnf_g, lnf_b, abuf);
    // proj head: split-K=4 atomic into zeroed fp32 buffer, then cvt to bf16
    zero_f32<<<(BT * DOUT) / 256, 256, 0, stream>>>(projacc, BT * DOUT);
    gemm_bt<0, 0, 0, 1><<<dim3(DOUT / 128, BT / 128, 4), 256, 0, stream>>>(
        abuf, proj_t, proj_b, nullptr, projacc, nullptr, DOUT, CDIM, CDIM / 4);
    cvt_bf16<<<(BT * DOUT) / 256, 256, 0, stream>>>(projacc, feats, BT * DOUT);
    gemm_bt<2, 0, 0, 0><<<dim3(DOUT / 128, BT / 128, 1), 256, 0, stream>>>(
        feats, dec1_t, dec_b1, nullptr, d1, nullptr, DOUT, DOUT, DOUT);
    ln_kernel<1><<<BT, 256, 0, stream>>>(d1, dec_ln_g, dec_ln_b, d1n);
    gemm_bt<0, 0, 0, 0><<<dim3(DIN / 128, BT / 128, 1), 256, 0, stream>>>(
        d1n, dec2_t, dec_b2, nullptr, pred, nullptr, DIN, DOUT, DOUT);
    int total = NBATCH * (TSEQ - 1) * DIN;
    out_sub<<<(total + 255) / 256, 256, 0, stream>>>(pred, tokens, (float*)d_out, total);
}

// Round 3
// 2842.579 us; speedup vs baseline: 1.1484x; 1.1037x over previous
//
#include <hip/hip_runtime.h>
#include <hip/hip_bf16.h>

typedef unsigned short u16;
typedef __attribute__((ext_vector_type(8))) short bf16x8;
typedef __attribute__((ext_vector_type(4))) float f32x4;

#define BT     4096
#define CDIM   1024
#define NH     16
#define FF     4096
#define DIN    128
#define DOUT   256
#define NLAYER 8
#define TSEQ   1024
#define NBATCH 4

__device__ inline u16 f2bfu(float v) {
    __hip_bfloat16 h = __float2bfloat16(v);
    return __builtin_bit_cast(unsigned short, h);
}

__device__ inline void async_copy16(const u16* g, u16* l) {
    __builtin_amdgcn_global_load_lds((const __attribute__((address_space(1))) void*)g,
                                     (__attribute__((address_space(3))) void*)l,
                                     16, 0, 0);
}

// ---------------- GEMM: C[M,N] = act(A[M,K] @ Bt[N,K]^T + bias) ----------------
// 128x128 tile, BK=32, 4 waves 2x2, 4x4 mfma_16x16x32_bf16 per wave.
// EPI: 0 = store (OBF: bf16/f32, RES: +res, ACT: 0 none / 1 gelu / 2 tanh)
//      1 = f32 atomicAdd into outp (split-K; bias added by z==0 only)
//      2 = QKV split store: cols<2048 -> qk row-major (stride 2048), cols>=2048 -> vT[b,h,f,t]
template<int ACT, int RES, int OBF, int EPI>
__global__ __launch_bounds__(256) void gemm_bt(
    const u16* __restrict__ A, const u16* __restrict__ Bt,
    const float* __restrict__ bias, const float* res,
    void* outp, u16* __restrict__ vtp, int N, int K, int Kc)
{
    __shared__ __align__(16) u16 As[128 * 32];
    __shared__ __align__(16) u16 Bs[128 * 32];
    int tid  = threadIdx.x;
    int wave = tid >> 6, lane = tid & 63;
    int ln = lane & 15, quad = lane >> 4;
    int wm = (wave >> 1) * 64, wn = (wave & 1) * 64;
    int k0 = blockIdx.z * Kc;
    const u16* Ab = A  + (size_t)blockIdx.y * 128 * K;
    const u16* Bb = Bt + (size_t)blockIdx.x * 128 * K;
    f32x4 acc[4][4] = {};
    for (int kt = k0; kt < k0 + Kc; kt += 32) {
#pragma unroll
        for (int it = 0; it < 2; ++it) {
            int e = it * 256 + tid;
            int row = e >> 2, col = (e & 3) * 8;
            int lbase = (it * 256 + wave * 64) * 8;   // wave-uniform LDS base
            async_copy16(Ab + (size_t)row * K + kt + col, As + lbase);
            async_copy16(Bb + (size_t)row * K + kt + col, Bs + lbase);
        }
        __syncthreads();
        bf16x8 af[4], bfr[4];
#pragma unroll
        for (int i = 0; i < 4; ++i)
            af[i] = *(const bf16x8*)&As[(wm + i * 16 + ln) * 32 + quad * 8];
#pragma unroll
        for (int j = 0; j < 4; ++j)
            bfr[j] = *(const bf16x8*)&Bs[(wn + j * 16 + ln) * 32 + quad * 8];
#pragma unroll
        for (int i = 0; i < 4; ++i)
#pragma unroll
            for (int j = 0; j < 4; ++j)
                acc[i][j] = __builtin_amdgcn_mfma_f32_16x16x32_bf16(af[i], bfr[j], acc[i][j], 0, 0, 0);
        __syncthreads();
    }
    int gr0 = blockIdx.y * 128 + wm + quad * 4;
    int gc0 = blockIdx.x * 128 + wn + ln;
#pragma unroll
    for (int i = 0; i < 4; ++i) {
#pragma unroll
        for (int j = 0; j < 4; ++j) {
            int gc = gc0 + j * 16;
            float bv = (EPI == 1) ? ((blockIdx.z == 0) ? bias[gc] : 0.0f) : bias[gc];
#pragma unroll
            for (int r = 0; r < 4; ++r) {
                int gr = gr0 + i * 16 + r;
                float v = acc[i][j][r] + bv;
                if (ACT == 1) v = 0.5f * v * (1.0f + erff(v * 0.70710678118654752f)); // exact gelu
                if (ACT == 2) v = tanhf(v);
                if (EPI == 1) {
                    unsafeAtomicAdd(&((float*)outp)[(size_t)gr * N + gc], v);
                } else if (EPI == 2) {
                    if ((int)blockIdx.x < 16) {
                        ((u16*)outp)[(size_t)gr * 2048 + gc] = f2bfu(v);
                    } else {
                        int c2 = gc - 2048;
                        int hh = c2 >> 6, f = c2 & 63;
                        int bb = gr >> 10, t = gr & 1023;
                        vtp[((size_t)(bb * 16 + hh) * 64 + f) * TSEQ + t] = f2bfu(v);
                    }
                } else {
                    size_t idx = (size_t)gr * N + gc;
                    if (RES) v += res[idx];
                    if (OBF) ((u16*)outp)[idx] = f2bfu(v);
                    else     ((float*)outp)[idx] = v;
                }
            }
        }
    }
}

// ---------------- Flash attention v3: K-split across 4 waves, merge at end ----------------
// qk: [b, t, 2048] (Q cols 0..1023, K cols 1024..2047), vT: [b*16+h, f(64), t]
// Flat grid 2048: id%8 pins bh->XCD (L2 locality), qt descending (load balance).
__global__ __launch_bounds__(256) void attn_kernel(const u16* __restrict__ qk,
    const u16* __restrict__ vT, u16* __restrict__ y)
{
    __shared__ __align__(16) float Osm[4][32][64];   // 32 KB, per-wave slices
    __shared__ float msm[4][32], lsm[4][32];
    int id = blockIdx.x;
    int bh = (id & 7) + 8 * ((id >> 3) & 7);
    int qt = 31 - (id >> 6);
    int b = bh >> 4, h = bh & 15;
    int q0 = qt * 32;
    int tid = threadIdx.x;
    int wave = tid >> 6, lane = tid & 63;
    int ln = lane & 15, quad = lane >> 4;
    // per-wave P staging aliases the head of this wave's Osm slice (exclusive use)
    u16* P0 = (u16*)&Osm[wave][0][0];        // 16x32 bf16
    u16* P1 = P0 + 512;                      // 16x32 bf16

    const u16* qbase = qk + (size_t)b * TSEQ * 2048;
    bf16x8 qf[2][2];
#pragma unroll
    for (int qi = 0; qi < 2; ++qi) {
        const u16* qrow = qbase + (size_t)(q0 + qi * 16 + ln) * 2048 + h * 64 + quad * 8;
        qf[qi][0] = *(const bf16x8*)qrow;
        qf[qi][1] = *(const bf16x8*)(qrow + 32);
    }
    const u16* vbase = vT + (size_t)bh * 64 * TSEQ;
    f32x4 O[2][4] = {};
    float m_i[2][4], l_i[2][4];
#pragma unroll
    for (int qi = 0; qi < 2; ++qi)
#pragma unroll
        for (int r = 0; r < 4; ++r) { m_i[qi][r] = -1e30f; l_i[qi][r] = 0.0f; }

    int nkt = qt + 1;
    for (int kt = wave; kt < nkt; kt += 4) {
        int j0 = kt * 32;
        bf16x8 kf[2][2];
#pragma unroll
        for (int kk = 0; kk < 2; ++kk) {
            const u16* krow = qbase + (size_t)(j0 + kk * 16 + ln) * 2048 + 1024 + h * 64 + quad * 8;
            kf[kk][0] = *(const bf16x8*)krow;
            kf[kk][1] = *(const bf16x8*)(krow + 32);
        }
        f32x4 S[2][2] = {};
#pragma unroll
        for (int qi = 0; qi < 2; ++qi)
#pragma unroll
            for (int kk = 0; kk < 2; ++kk) {
                S[qi][kk] = __builtin_amdgcn_mfma_f32_16x16x32_bf16(qf[qi][0], kf[kk][0], S[qi][kk], 0, 0, 0);
                S[qi][kk] = __builtin_amdgcn_mfma_f32_16x16x32_bf16(qf[qi][1], kf[kk][1], S[qi][kk], 0, 0, 0);
            }
        bool lastt = (kt == qt);
        float alpha[2][4];
#pragma unroll
        for (int qi = 0; qi < 2; ++qi) {
#pragma unroll
            for (int r = 0; r < 4; ++r) {
                float s0 = S[qi][0][r] * 0.125f, s1 = S[qi][1][r] * 0.125f;
                if (lastt) {
                    int qr = q0 + qi * 16 + quad * 4 + r;
                    if (j0 + ln > qr)      s0 = -1e30f;
                    if (j0 + 16 + ln > qr) s1 = -1e30f;
                }
                float mx = fmaxf(s0, s1);
                mx = fmaxf(mx, __shfl_xor(mx, 1));
                mx = fmaxf(mx, __shfl_xor(mx, 2));
                mx = fmaxf(mx, __shfl_xor(mx, 4));
                mx = fmaxf(mx, __shfl_xor(mx, 8));
                float mn = fmaxf(m_i[qi][r], mx);
                float al = __expf(m_i[qi][r] - mn);
                float p0 = __expf(s0 - mn);
                float p1 = __expf(s1 - mn);
                float rs = p0 + p1;
                rs += __shfl_xor(rs, 1);
                rs += __shfl_xor(rs, 2);
                rs += __shfl_xor(rs, 4);
                rs += __shfl_xor(rs, 8);
                l_i[qi][r] = l_i[qi][r] * al + rs;
                m_i[qi][r] = mn;
                alpha[qi][r] = al;
                u16* Pq = qi ? P1 : P0;
                Pq[(quad * 4 + r) * 32 + ln]      = f2bfu(p0);
                Pq[(quad * 4 + r) * 32 + 16 + ln] = f2bfu(p1);
            }
#pragma unroll
            for (int nt = 0; nt < 4; ++nt)
#pragma unroll
                for (int r = 0; r < 4; ++r)
                    O[qi][nt][r] *= alpha[qi][r];
        }
        // intra-wave LDS roundtrip: lgkmcnt ordering, no barrier needed
        bf16x8 pa0 = *(const bf16x8*)&P0[ln * 32 + quad * 8];
        bf16x8 pa1 = *(const bf16x8*)&P1[ln * 32 + quad * 8];
#pragma unroll
        for (int nt = 0; nt < 4; ++nt) {
            bf16x8 vf = *(const bf16x8*)(vbase + (size_t)(nt * 16 + ln) * TSEQ + j0 + quad * 8);
            O[0][nt] = __builtin_amdgcn_mfma_f32_16x16x32_bf16(pa0, vf, O[0][nt], 0, 0, 0);
            O[1][nt] = __builtin_amdgcn_mfma_f32_16x16x32_bf16(pa1, vf, O[1][nt], 0, 0, 0);
        }
    }
    // write partial state (overwrites this wave's P region — wave is done with it)
#pragma unroll
    for (int qi = 0; qi < 2; ++qi)
#pragma unroll
        for (int r = 0; r < 4; ++r) {
            int row = qi * 16 + quad * 4 + r;
            if (ln == 0) { msm[wave][row] = m_i[qi][r]; lsm[wave][row] = l_i[qi][r]; }
#pragma unroll
            for (int nt = 0; nt < 4; ++nt)
                Osm[wave][row][nt * 16 + ln] = O[qi][nt][r];
        }
    __syncthreads();
    // merge: 256 threads cover 32 rows x 64 cols, 8 cols each
    {
        int row = tid >> 3;
        int c0 = (tid & 7) * 8;
        float m0 = msm[0][row], m1 = msm[1][row], m2 = msm[2][row], m3 = msm[3][row];
        float ms = fmaxf(fmaxf(m0, m1), fmaxf(m2, m3));
        float e0 = __expf(m0 - ms), e1 = __expf(m1 - ms), e2 = __expf(m2 - ms), e3 = __expf(m3 - ms);
        float ls = lsm[0][row] * e0 + lsm[1][row] * e1 + lsm[2][row] * e2 + lsm[3][row] * e3;
        float inv = 1.0f / ls;
        u16* yr = y + (size_t)(b * TSEQ + q0 + row) * CDIM + h * 64 + c0;
#pragma unroll
        for (int j = 0; j < 8; ++j) {
            float o = Osm[0][row][c0 + j] * e0 + Osm[1][row][c0 + j] * e1
                    + Osm[2][row][c0 + j] * e2 + Osm[3][row][c0 + j] * e3;
            yr[j] = f2bfu(o * inv);
        }
    }
}

// ---------------- LayerNorm (row of NPT*256 fp32 -> bf16) ----------------
template<int NPT>
__global__ __launch_bounds__(256) void ln_kernel(const float* __restrict__ x,
    const float* __restrict__ g, const float* __restrict__ bet, u16* __restrict__ out)
{
    const int n = NPT * 256;
    int row = blockIdx.x, tid = threadIdx.x;
    const float* xr = x + (size_t)row * n;
    float xv[NPT];
    float s1 = 0.f, s2 = 0.f;
#pragma unroll
    for (int k = 0; k < NPT; ++k) {
        float v = xr[k * 256 + tid];
        xv[k] = v; s1 += v; s2 += v * v;
    }
#pragma unroll
    for (int m = 1; m < 64; m <<= 1) { s1 += __shfl_xor(s1, m); s2 += __shfl_xor(s2, m); }
    __shared__ float red[8];
    int wv = tid >> 6;
    if ((tid & 63) == 0) { red[wv] = s1; red[4 + wv] = s2; }
    __syncthreads();
    s1 = red[0] + red[1] + red[2] + red[3];
    s2 = red[4] + red[5] + red[6] + red[7];
    float mu = s1 * (1.0f / n);
    float var = s2 * (1.0f / n) - mu * mu;
    float rs = rsqrtf(var + 1e-5f);
#pragma unroll
    for (int k = 0; k < NPT; ++k) {
        int c = k * 256 + tid;
        out[(size_t)row * n + c] = f2bfu((xv[k] - mu) * rs * g[c] + bet[c]);
    }
}

// ---------------- 32x32 transpose + fp32->bf16: dst[N,K] = bf16(src[K,N]^T) ----------------
__device__ inline void tile_tc(const float* src, u16* dst, int K, int N, int kt, int nt,
                               int tid, float* sm)
{
    int c = tid & 31, r0 = tid >> 5;
#pragma unroll
    for (int rr = r0; rr < 32; rr += 8)
        sm[rr * 33 + c] = src[(size_t)(kt * 32 + rr) * N + nt * 32 + c];
    __syncthreads();
#pragma unroll
    for (int rr = r0; rr < 32; rr += 8)
        dst[(size_t)(nt * 32 + rr) * K + kt * 32 + c] = f2bfu(sm[c * 33 + rr]);
}

__global__ __launch_bounds__(256) void transpose_cvt(const float* __restrict__ src,
    u16* __restrict__ dst, int K, int N)
{
    __shared__ float sm[32 * 33];
    tile_tc(src, dst, K, N, blockIdx.y, blockIdx.x, threadIdx.x, sm);
}

// Fused per-layer weight prep
__global__ __launch_bounds__(256) void prep_layer(
    const float* __restrict__ Wq, const float* __restrict__ Wk, const float* __restrict__ Wv,
    const float* __restrict__ Wo, const float* __restrict__ W1, const float* __restrict__ W2,
    const float* __restrict__ bq, const float* __restrict__ bk, const float* __restrict__ bv,
    u16* __restrict__ qkv_t, u16* __restrict__ wo_t, u16* __restrict__ w1_t,
    u16* __restrict__ w2_t, float* __restrict__ bias3)
{
    __shared__ float sm[32 * 33];
    int id = blockIdx.x, tid = threadIdx.x;
    const float* src; u16* dst; int K, N, kt, nt;
    if (id < 3072) {
        int w = id >> 10, t = id & 1023;
        src = (w == 0) ? Wq : ((w == 1) ? Wk : Wv);
        dst = qkv_t + (size_t)w * CDIM * CDIM;
        K = CDIM; N = CDIM; kt = t >> 5; nt = t & 31;
    } else if (id < 4096) {
        int t = id - 3072; src = Wo; dst = wo_t; K = CDIM; N = CDIM; kt = t >> 5; nt = t & 31;
    } else if (id < 8192) {
        int t = id - 4096; src = W1; dst = w1_t; K = CDIM; N = FF;   kt = t >> 7; nt = t & 127;
    } else {
        int t = id - 8192; src = W2; dst = w2_t; K = FF;   N = CDIM; kt = t >> 5; nt = t & 31;
    }
    tile_tc(src, dst, K, N, kt, nt, tid, sm);
    if (id < 3) {
        const float* bsrc = (id == 0) ? bq : ((id == 1) ? bk : bv);
        for (int k2 = tid; k2 < CDIM; k2 += 256) bias3[id * CDIM + k2] = bsrc[k2];
    }
}

__global__ __launch_bounds__(256) void cvt_bf16(const float* __restrict__ src,
    u16* __restrict__ dst, int n)
{
    int i = blockIdx.x * 256 + threadIdx.x;
    if (i < n) dst[i] = f2bfu(src[i]);
}

__global__ __launch_bounds__(256) void zero_f32(float* __restrict__ dst, int n)
{
    int i = blockIdx.x * 256 + threadIdx.x;
    if (i < n) dst[i] = 0.0f;
}

__global__ __launch_bounds__(256) void out_sub(const float* __restrict__ pred,
    const float* __restrict__ x, float* __restrict__ out, int total)
{
    int i = blockIdx.x * 256 + threadIdx.x;
    if (i >= total) return;
    int b = i / ((TSEQ - 1) * DIN);
    int rtmp = i - b * (TSEQ - 1) * DIN;
    int t = rtmp >> 7, f = rtmp & 127;
    out[i] = pred[(size_t)(b * TSEQ + t) * DIN + f] - x[(size_t)(b * TSEQ + t + 1) * DIN + f];
}

__global__ void fail_flag(float* out) { if (threadIdx.x == 0 && blockIdx.x == 0) out[0] = 1.0e6f; }

extern "C" void kernel_launch(void* const* d_in, const int* in_sizes, int n_in,
                              void* d_out, int out_size, void* d_ws, size_t ws_size,
                              hipStream_t stream)
{
    (void)in_sizes; (void)n_in; (void)out_size;
    const float* tokens    = (const float*)d_in[0];
    const float* tok_emb_w = (const float*)d_in[1];
    const float* tok_emb_b = (const float*)d_in[2];
    const float* ln1_g = (const float*)d_in[3];
    const float* ln1_b = (const float*)d_in[4];
    const float* Wq = (const float*)d_in[5];
    const float* bq = (const float*)d_in[6];
    const float* Wk = (const float*)d_in[7];
    const float* bk = (const float*)d_in[8];
    const float* Wv = (const float*)d_in[9];
    const float* bv = (const float*)d_in[10];
    const float* Wo = (const float*)d_in[11];
    const float* bo = (const float*)d_in[12];
    const float* ln2_g = (const float*)d_in[13];
    const float* ln2_b = (const float*)d_in[14];
    const float* W1 = (const float*)d_in[15];
    const float* b1 = (const float*)d_in[16];
    const float* W2 = (const float*)d_in[17];
    const float* b2 = (const float*)d_in[18];
    const float* lnf_g = (const float*)d_in[19];
    const float* lnf_b = (const float*)d_in[20];
    const float* proj_w = (const float*)d_in[21];
    const float* proj_b = (const float*)d_in[22];
    const float* dec_w1 = (const float*)d_in[23];
    const float* dec_b1 = (const float*)d_in[24];
    const float* dec_ln_g = (const float*)d_in[25];
    const float* dec_ln_b = (const float*)d_in[26];
    const float* dec_w2 = (const float*)d_in[27];
    const float* dec_b2 = (const float*)d_in[28];

    char* p = (char*)d_ws;
    auto alloc = [&](size_t bytes) -> char* {
        char* r = p; p += (bytes + 255) & ~(size_t)255; return r;
    };
    u16*   xb      = (u16*)  alloc((size_t)BT * DIN * 2);
    float* h       = (float*)alloc((size_t)BT * CDIM * 4);
    u16*   abuf    = (u16*)  alloc((size_t)BT * CDIM * 2);
    u16*   qkb     = (u16*)  alloc((size_t)BT * 2048 * 2);       // Q,K
    u16*   vTb     = (u16*)  alloc((size_t)NBATCH * NH * 64 * TSEQ * 2);  // V transposed
    u16*   yb      = (u16*)  alloc((size_t)BT * CDIM * 2);
    u16*   t1      = (u16*)  alloc((size_t)BT * FF * 2);
    u16*   feats   = (u16*)  alloc((size_t)BT * DOUT * 2);
    float* projacc = (float*)alloc((size_t)BT * DOUT * 4);
    float* d1      = (float*)alloc((size_t)BT * DOUT * 4);
    u16*   d1n     = (u16*)  alloc((size_t)BT * DOUT * 2);
    float* pred    = (float*)alloc((size_t)BT * DIN * 4);
    u16*   emb_t   = (u16*)  alloc((size_t)CDIM * DIN * 2);
    u16*   proj_t  = (u16*)  alloc((size_t)DOUT * CDIM * 2);
    u16*   dec1_t  = (u16*)  alloc((size_t)DOUT * DOUT * 2);
    u16*   dec2_t  = (u16*)  alloc((size_t)DIN * DOUT * 2);
    u16*   qkv_t   = (u16*)  alloc((size_t)3 * CDIM * CDIM * 2);
    u16*   wo_t    = (u16*)  alloc((size_t)CDIM * CDIM * 2);
    u16*   w1_t    = (u16*)  alloc((size_t)FF * CDIM * 2);
    u16*   w2_t    = (u16*)  alloc((size_t)CDIM * FF * 2);
    float* bias3   = (float*)alloc((size_t)3 * CDIM * 4);
    if ((size_t)(p - (char*)d_ws) > ws_size) {
        fail_flag<<<1, 64, 0, stream>>>((float*)d_out);
        return;
    }

    cvt_bf16<<<(BT * DIN) / 256, 256, 0, stream>>>(tokens, xb, BT * DIN);
    transpose_cvt<<<dim3(CDIM / 32, DIN / 32),  256, 0, stream>>>(tok_emb_w, emb_t,  DIN,  CDIM);
    transpose_cvt<<<dim3(DOUT / 32, CDIM / 32), 256, 0, stream>>>(proj_w,    proj_t, CDIM, DOUT);
    transpose_cvt<<<dim3(DOUT / 32, DOUT / 32), 256, 0, stream>>>(dec_w1,    dec1_t, DOUT, DOUT);
    transpose_cvt<<<dim3(DIN / 32,  DOUT / 32), 256, 0, stream>>>(dec_w2,    dec2_t, DOUT, DIN);
    // h = xb @ emb_t^T + b  (fp32 out)
    gemm_bt<0, 0, 0, 0><<<dim3(CDIM / 128, BT / 128, 1), 256, 0, stream>>>(
        xb, emb_t, tok_emb_b, nullptr, h, nullptr, CDIM, DIN, DIN);

    for (int l = 0; l < NLAYER; ++l) {
        prep_layer<<<12288, 256, 0, stream>>>(
            Wq + (size_t)l * CDIM * CDIM, Wk + (size_t)l * CDIM * CDIM,
            Wv + (size_t)l * CDIM * CDIM, Wo + (size_t)l * CDIM * CDIM,
            W1 + (size_t)l * CDIM * FF,   W2 + (size_t)l * FF * CDIM,
            bq + l * CDIM, bk + l * CDIM, bv + l * CDIM,
            qkv_t, wo_t, w1_t, w2_t, bias3);
        ln_kernel<4><<<BT, 256, 0, stream>>>(h, ln1_g + l * CDIM, ln1_b + l * CDIM, abuf);
        // QKV: Q,K -> qkb, V -> vTb (transposed)
        gemm_bt<0, 0, 1, 2><<<dim3(3 * CDIM / 128, BT / 128, 1), 256, 0, stream>>>(
            abuf, qkv_t, bias3, nullptr, qkb, vTb, 3 * CDIM, CDIM, CDIM);
        attn_kernel<<<2048, 256, 0, stream>>>(qkb, vTb, yb);
        // o-proj: split-K=2, atomic into residual h
        gemm_bt<0, 0, 0, 1><<<dim3(CDIM / 128, BT / 128, 2), 256, 0, stream>>>(
            yb, wo_t, bo + l * CDIM, nullptr, h, nullptr, CDIM, CDIM, CDIM / 2);
        ln_kernel<4><<<BT, 256, 0, stream>>>(h, ln2_g + l * CDIM, ln2_b + l * CDIM, abuf);
        gemm_bt<1, 0, 1, 0><<<dim3(FF / 128, BT / 128, 1), 256, 0, stream>>>(
            abuf, w1_t, b1 + l * FF, nullptr, t1, nullptr, FF, CDIM, CDIM);
        // MLP2: split-K=2, atomic into residual h
        gemm_bt<0, 0, 0, 1><<<dim3(CDIM / 128, BT / 128, 2), 256, 0, stream>>>(
            t1, w2_t, b2 + l * CDIM, nullptr, h, nullptr, CDIM, FF, FF / 2);
    }

    ln_kernel<4><<<BT, 256, 0, stream>>>(h, lnf_g, lnf_b, abuf);
    // proj head: split-K=4 atomic into zeroed fp32 buffer, then cvt to bf16
    zero_f32<<<(BT * DOUT) / 256, 256, 0, stream>>>(projacc, BT * DOUT);
    gemm_bt<0, 0, 0, 1><<<dim3(DOUT / 128, BT / 128, 4), 256, 0, stream>>>(
        abuf, proj_t, proj_b, nullptr, projacc, nullptr, DOUT, CDIM, CDIM / 4);
    cvt_bf16<<<(BT * DOUT) / 256, 256, 0, stream>>>(projacc, feats, BT * DOUT);
    gemm_bt<2, 0, 0, 0><<<dim3(DOUT / 128, BT / 128, 1), 256, 0, stream>>>(
        feats, dec1_t, dec_b1, nullptr, d1, nullptr, DOUT, DOUT, DOUT);
    ln_kernel<1><<<BT, 256, 0, stream>>>(d1, dec_ln_g, dec_ln_b, d1n);
    gemm_bt<0, 0, 0, 0><<<dim3(DIN / 128, BT / 128, 1), 256, 0, stream>>>(
        d1n, dec2_t, dec_b2, nullptr, pred, nullptr, DIN, DOUT, DOUT);
    int total = NBATCH * (TSEQ - 1) * DIN;
    out_sub<<<(total + 255) / 256, 256, 0, stream>>>(pred, tokens, (float*)d_out, total);
}